// Round 11
// baseline (643.912 us; speedup 1.0000x reference)
//
#include <hip/hip_runtime.h>
#include <hip/hip_bf16.h>

#define HID 64
#define RPW 16   // rows per wave in gemm2_reg
#define KCH 8    // k-chunk width (W regs live at a time = 2*KCH)

// -------- fused dual GEMM, K-chunked register tiling, SCALAR row broadcast.
// (R10 version, unchanged: 55us on n3, at its in-place ~2TB/s point.)
template <int KC>
__global__ __attribute__((amdgpu_flat_work_group_size(256, 256),
                          amdgpu_waves_per_eu(6, 6)))
void gemm2_reg(const float* in,
               const float* __restrict__ Wa, const float* __restrict__ Wb,
               float* outa, float* outb,
               int R, int ldw, int coloff) {
    int lane = threadIdx.x & 63;
    int wid = blockIdx.x * (blockDim.x >> 6) + (threadIdx.x >> 6);
    int j0 = __builtin_amdgcn_readfirstlane(wid * RPW);
    if (j0 >= R) return;                       // uniform branch
    float accx[RPW], accy[RPW];
#pragma unroll
    for (int r = 0; r < RPW; ++r) { accx[r] = 0.f; accy[r] = 0.f; }
    const float* pa = Wa + (size_t)lane * ldw + coloff;
    const float* pb = Wb + (size_t)lane * ldw + coloff;
#pragma unroll 1
    for (int kc = 0; kc < KC; kc += KCH) {
        float wx[KCH], wy[KCH];
#pragma unroll
        for (int kk = 0; kk < KCH; ++kk) { wx[kk] = pa[kc + kk]; wy[kk] = pb[kc + kk]; }
#pragma unroll
        for (int r = 0; r < RPW; ++r) {
            const float* rp = in + (size_t)(j0 + r) * KC + kc;   // uniform ptr
#pragma unroll
            for (int kk = 0; kk < KCH; ++kk) {
                float s = rp[kk];              // uniform load -> s_load
                accx[r] = fmaf(s, wx[kk], accx[r]);
                accy[r] = fmaf(s, wy[kk], accy[r]);
            }
        }
    }
#pragma unroll
    for (int r = 0; r < RPW; ++r) {
        int j = j0 + r;
        outa[(size_t)j * HID + lane] = accx[r];
        outb[(size_t)j * HID + lane] = accy[r];
    }
}

// ======== batched CSR build: each stage covers all 3 edge sets ========
__global__ void zero4_k(int* p1, int s1, int* p2, int s2, int* p3, int s3,
                        int* p4, int s4, int nb1, int nb2, int nb3) {
    int b = blockIdx.x; int* p; int n; int lb;
    if (b < nb1)                 { p = p1; n = s1; lb = b; }
    else if (b < nb1 + nb2)      { p = p2; n = s2; lb = b - nb1; }
    else if (b < nb1 + nb2 + nb3){ p = p3; n = s3; lb = b - nb1 - nb2; }
    else                         { p = p4; n = s4; lb = b - nb1 - nb2 - nb3; }
    int i = lb * 256 + threadIdx.x;
    if (i < n) p[i] = 0;
}

__global__ void hist3_k(const int* e1, int E1, int* c1,
                        const int* e2, int E2, int* c2,
                        const int* e3, int E3, int* c3, int nb1, int nb2) {
    int b = blockIdx.x; const int* dst; int* c; int E; int lb;
    if (b < nb1)            { dst = e1 + E1; c = c1; E = E1; lb = b; }
    else if (b < nb1 + nb2) { dst = e2 + E2; c = c2; E = E2; lb = b - nb1; }
    else                    { dst = e3 + E3; c = c3; E = E3; lb = b - nb1 - nb2; }
    int e = lb * 256 + threadIdx.x;
    if (e < E) atomicAdd(&c[dst[e]], 1);
}

__device__ __forceinline__ void scan1_body(const int* __restrict__ cnt, int* __restrict__ rs,
                                           int* __restrict__ bsum, int n1, int n, int lb) {
    __shared__ int wsum[4];
    int t = threadIdx.x;
    int base = lb * 1024 + t * 4;
    int v[4]; int s = 0;
#pragma unroll
    for (int i = 0; i < 4; ++i) { int idx = base + i; v[i] = s; s += (idx < n) ? cnt[idx] : 0; }
    int lane = t & 63, wv = t >> 6;
    int x = s;
#pragma unroll
    for (int off = 1; off < 64; off <<= 1) { int y = __shfl_up(x, off, 64); if (lane >= off) x += y; }
    if (lane == 63) wsum[wv] = x;
    __syncthreads();
    int woff = 0;
    for (int w = 0; w < wv; ++w) woff += wsum[w];
    int excl = woff + (x - s);
#pragma unroll
    for (int i = 0; i < 4; ++i) { int idx = base + i; if (idx < n1) rs[idx] = excl + v[i]; }
    if (t == 255) bsum[lb] = wsum[0] + wsum[1] + wsum[2] + wsum[3];
}

__global__ void scan1_3k(const int* c1, int* r1, int* b1, int n1a, int na,
                         const int* c2, int* r2, int* b2, int n1b, int nb,
                         const int* c3, int* r3, int* b3, int n1c, int nc,
                         int nbl1, int nbl2) {
    int b = blockIdx.x;
    if (b < nbl1)             scan1_body(c1, r1, b1, n1a, na, b);
    else if (b < nbl1 + nbl2) scan1_body(c2, r2, b2, n1b, nb, b - nbl1);
    else                      scan1_body(c3, r3, b3, n1c, nc, b - nbl1 - nbl2);
}

__device__ __forceinline__ void scan2_body(int* bsum, int nb, int* wsum) {
    int t = threadIdx.x;
    int s = (t < nb) ? bsum[t] : 0;
    int lane = t & 63, wv = t >> 6;
    int x = s;
#pragma unroll
    for (int off = 1; off < 64; off <<= 1) { int y = __shfl_up(x, off, 64); if (lane >= off) x += y; }
    if (lane == 63) wsum[wv] = x;
    __syncthreads();
    int woff = 0;
    for (int w = 0; w < wv; ++w) woff += wsum[w];
    if (t < nb) bsum[t] = woff + x - s;   // exclusive
    __syncthreads();                       // before wsum reuse
}

__global__ void scan2_3k(int* b1, int nb1, int* b2, int nb2, int* b3, int nb3) {
    __shared__ int wsum[4];
    scan2_body(b1, nb1, wsum);
    scan2_body(b2, nb2, wsum);
    scan2_body(b3, nb3, wsum);
}

__global__ void scan3_3k(int* r1, const int* b1, int n1a,
                         int* r2, const int* b2, int n1b,
                         int* r3, const int* b3, int n1c, int nc1, int nc2) {
    int b = blockIdx.x; int* rs; const int* bsum; int n1; int lb;
    if (b < nc1)            { rs = r1; bsum = b1; n1 = n1a; lb = b; }
    else if (b < nc1 + nc2) { rs = r2; bsum = b2; n1 = n1b; lb = b - nc1; }
    else                    { rs = r3; bsum = b3; n1 = n1c; lb = b - nc1 - nc2; }
    int i = lb * 256 + threadIdx.x;
    if (i < n1) rs[i] += bsum[lb >> 2];
}

__global__ void fill3_k(const int* e1, int E1, const int* r1, int* c1, int* s1,
                        const int* e2, int E2, const int* r2, int* c2, int* s2,
                        const int* e3, int E3, const int* r3, int* c3, int* s3,
                        int nb1, int nb2) {
    int b = blockIdx.x;
    const int* edges; int E; const int* rs; int* cur; int* csrc; int lb;
    if (b < nb1)            { edges = e1; E = E1; rs = r1; cur = c1; csrc = s1; lb = b; }
    else if (b < nb1 + nb2) { edges = e2; E = E2; rs = r2; cur = c2; csrc = s2; lb = b - nb1; }
    else                    { edges = e3; E = E3; rs = r3; cur = c3; csrc = s3; lb = b - nb1 - nb2; }
    int e = lb * 256 + threadIdx.x;
    if (e >= E) return;
    int d = edges[E + e];
    int p = rs[d] + atomicAdd(&cur[d], 1);
    csrc[p] = edges[e];
}

// -------- plain gather + relu (used for layer 1 of each level)
// float2 lanes: wave covers 2 rows (lane>>5) x 32 feature-pairs (lane&31).
__global__ void neighsum_relu_k(const int* __restrict__ rs, const int* __restrict__ csrc,
                                const float* __restrict__ m, float* __restrict__ z,
                                int R, int nb8) {
    int b = (int)(blockIdx.x & 7) * nb8 + (int)(blockIdx.x >> 3);
    int t = threadIdx.x;
    int wv = t >> 6, lane = t & 63;
    int j = b * 8 + wv * 2 + (lane >> 5);   // 8 rows per block
    int f2 = lane & 31;
    if (j >= R) return;
    const float2* m2 = (const float2*)m;
    float2* z2p = (float2*)z;
    int s = rs[j], e = rs[j + 1];
    float2 a = z2p[(size_t)j * 32 + f2];
    float ax = a.x, ay = a.y;
    int k = s;
    for (; k + 8 <= e; k += 8) {
        int i0 = csrc[k],     i1 = csrc[k + 1], i2 = csrc[k + 2], i3 = csrc[k + 3];
        int i4 = csrc[k + 4], i5 = csrc[k + 5], i6 = csrc[k + 6], i7 = csrc[k + 7];
        float2 v0 = m2[(size_t)i0 * 32 + f2], v1 = m2[(size_t)i1 * 32 + f2];
        float2 v2 = m2[(size_t)i2 * 32 + f2], v3 = m2[(size_t)i3 * 32 + f2];
        float2 v4 = m2[(size_t)i4 * 32 + f2], v5 = m2[(size_t)i5 * 32 + f2];
        float2 v6 = m2[(size_t)i6 * 32 + f2], v7 = m2[(size_t)i7 * 32 + f2];
        ax += ((v0.x + v1.x) + (v2.x + v3.x)) + ((v4.x + v5.x) + (v6.x + v7.x));
        ay += ((v0.y + v1.y) + (v2.y + v3.y)) + ((v4.y + v5.y) + (v6.y + v7.y));
    }
    for (; k + 4 <= e; k += 4) {
        int i0 = csrc[k], i1 = csrc[k + 1], i2 = csrc[k + 2], i3 = csrc[k + 3];
        float2 v0 = m2[(size_t)i0 * 32 + f2], v1 = m2[(size_t)i1 * 32 + f2];
        float2 v2 = m2[(size_t)i2 * 32 + f2], v3 = m2[(size_t)i3 * 32 + f2];
        ax += (v0.x + v1.x) + (v2.x + v3.x);
        ay += (v0.y + v1.y) + (v2.y + v3.y);
    }
    for (; k < e; ++k) {
        float2 v = m2[(size_t)csrc[k] * 32 + f2];
        ax += v.x; ay += v.y;
    }
    z2p[(size_t)j * 32 + f2] = make_float2(fmaxf(ax, 0.f), fmaxf(ay, 0.f));
}

// -------- FUSED level-2 layer-0: z2[j] = relu(zinit(j) + sum_s minit(s))
// zinit(j) = hU1[gu[j]] + hV1[gv[j]] + iso2[j]*W1[:,128]
// minit(s) = hU2[gu[s]] + hV2[gv[s]] + iso2[s]*W2[:,128]
// Tables hU*/hV* are N x 64 (655 KB each, L2-resident); this deletes the
// gather2_k materialization pass entirely.
__global__ void neighsum0_l2_k(const int* __restrict__ rs, const int* __restrict__ csrc,
                               const float* __restrict__ hU1, const float* __restrict__ hV1,
                               const float* __restrict__ hU2, const float* __restrict__ hV2,
                               const int* __restrict__ gu, const int* __restrict__ gv,
                               const float* __restrict__ iso2,
                               const float* __restrict__ W1, const float* __restrict__ W2,
                               float* __restrict__ z, int R, int nb8) {
    int b = (int)(blockIdx.x & 7) * nb8 + (int)(blockIdx.x >> 3);
    int t = threadIdx.x;
    int wv = t >> 6, lane = t & 63;
    int j = b * 8 + wv * 2 + (lane >> 5);
    int f2 = lane & 31;
    if (j >= R) return;
    float w1x = W1[(2 * f2) * 129 + 128],     w1y = W1[(2 * f2 + 1) * 129 + 128];
    float w2x = W2[(2 * f2) * 129 + 128],     w2y = W2[(2 * f2 + 1) * 129 + 128];
    const float2* U1 = (const float2*)hU1; const float2* V1 = (const float2*)hV1;
    const float2* U2 = (const float2*)hU2; const float2* V2 = (const float2*)hV2;
    int uj = gu[j], vj = gv[j];
    float isj = iso2[j];
    float2 vu = U1[(size_t)uj * 32 + f2], vv = V1[(size_t)vj * 32 + f2];
    float ax = vu.x + vv.x + isj * w1x;
    float ay = vu.y + vv.y + isj * w1y;
    int s = rs[j], e = rs[j + 1];
    int k = s;
    for (; k + 4 <= e; k += 4) {
        int s0 = csrc[k], s1 = csrc[k + 1], s2 = csrc[k + 2], s3 = csrc[k + 3];
        int u0 = gu[s0], v0 = gv[s0]; float i0 = iso2[s0];
        int u1 = gu[s1], v1 = gv[s1]; float i1 = iso2[s1];
        int u2 = gu[s2], v2 = gv[s2]; float i2 = iso2[s2];
        int u3 = gu[s3], v3 = gv[s3]; float i3 = iso2[s3];
        float2 a0 = U2[(size_t)u0 * 32 + f2], b0 = V2[(size_t)v0 * 32 + f2];
        float2 a1 = U2[(size_t)u1 * 32 + f2], b1 = V2[(size_t)v1 * 32 + f2];
        float2 a2 = U2[(size_t)u2 * 32 + f2], b2 = V2[(size_t)v2 * 32 + f2];
        float2 a3 = U2[(size_t)u3 * 32 + f2], b3 = V2[(size_t)v3 * 32 + f2];
        float isum = (i0 + i1) + (i2 + i3);
        ax += ((a0.x + b0.x) + (a1.x + b1.x)) + ((a2.x + b2.x) + (a3.x + b3.x)) + isum * w2x;
        ay += ((a0.y + b0.y) + (a1.y + b1.y)) + ((a2.y + b2.y) + (a3.y + b3.y)) + isum * w2y;
    }
    for (; k < e; ++k) {
        int s0 = csrc[k];
        int u0 = gu[s0], v0 = gv[s0]; float i0 = iso2[s0];
        float2 a0 = U2[(size_t)u0 * 32 + f2], b0 = V2[(size_t)v0 * 32 + f2];
        ax += a0.x + b0.x + i0 * w2x;
        ay += a0.y + b0.y + i0 * w2y;
    }
    ((float2*)z)[(size_t)j * 32 + f2] = make_float2(fmaxf(ax, 0.f), fmaxf(ay, 0.f));
}

// -------- FUSED level-3 layer-0 (iso3 one-hot over 4 classes; 4 fma each)
__global__ void neighsum0_l3_k(const int* __restrict__ rs, const int* __restrict__ csrc,
                               const float* __restrict__ hA1, const float* __restrict__ hB1,
                               const float* __restrict__ hC1,
                               const float* __restrict__ hA2, const float* __restrict__ hB2,
                               const float* __restrict__ hC2,
                               const int* __restrict__ ga, const int* __restrict__ gb,
                               const int* __restrict__ gc, const float* __restrict__ iso3,
                               const float* __restrict__ W1, const float* __restrict__ W2,
                               float* __restrict__ z, int R, int nb8) {
    int b = (int)(blockIdx.x & 7) * nb8 + (int)(blockIdx.x >> 3);
    int t = threadIdx.x;
    int wv = t >> 6, lane = t & 63;
    int j = b * 8 + wv * 2 + (lane >> 5);
    int f2 = lane & 31;
    if (j >= R) return;
    float w1x[4], w1y[4], w2x[4], w2y[4];
#pragma unroll
    for (int c = 0; c < 4; ++c) {
        w1x[c] = W1[(2 * f2) * 196 + 192 + c];
        w1y[c] = W1[(2 * f2 + 1) * 196 + 192 + c];
        w2x[c] = W2[(2 * f2) * 196 + 192 + c];
        w2y[c] = W2[(2 * f2 + 1) * 196 + 192 + c];
    }
    const float2* A1 = (const float2*)hA1; const float2* B1 = (const float2*)hB1;
    const float2* C1 = (const float2*)hC1;
    const float2* A2 = (const float2*)hA2; const float2* B2 = (const float2*)hB2;
    const float2* C2 = (const float2*)hC2;
    const float4* I4 = (const float4*)iso3;
    int aj = ga[j], bj = gb[j], cj = gc[j];
    float4 ij = I4[j];
    float2 va = A1[(size_t)aj * 32 + f2], vb = B1[(size_t)bj * 32 + f2],
           vc = C1[(size_t)cj * 32 + f2];
    float ax = va.x + vb.x + vc.x
             + ij.x * w1x[0] + ij.y * w1x[1] + ij.z * w1x[2] + ij.w * w1x[3];
    float ay = va.y + vb.y + vc.y
             + ij.x * w1y[0] + ij.y * w1y[1] + ij.z * w1y[2] + ij.w * w1y[3];
    int s = rs[j], e = rs[j + 1];
    int k = s;
    for (; k + 2 <= e; k += 2) {
        int s0 = csrc[k], s1 = csrc[k + 1];
        int a0 = ga[s0], b0 = gb[s0], c0 = gc[s0]; float4 i0 = I4[s0];
        int a1 = ga[s1], b1 = gb[s1], c1 = gc[s1]; float4 i1 = I4[s1];
        float2 p0 = A2[(size_t)a0 * 32 + f2], q0 = B2[(size_t)b0 * 32 + f2],
               r0 = C2[(size_t)c0 * 32 + f2];
        float2 p1 = A2[(size_t)a1 * 32 + f2], q1 = B2[(size_t)b1 * 32 + f2],
               r1 = C2[(size_t)c1 * 32 + f2];
        float sx = ij.x; (void)sx;
        float cx = i0.x + i1.x, cy = i0.y + i1.y, cz = i0.z + i1.z, cw = i0.w + i1.w;
        ax += (p0.x + q0.x + r0.x) + (p1.x + q1.x + r1.x)
            + cx * w2x[0] + cy * w2x[1] + cz * w2x[2] + cw * w2x[3];
        ay += (p0.y + q0.y + r0.y) + (p1.y + q1.y + r1.y)
            + cx * w2y[0] + cy * w2y[1] + cz * w2y[2] + cw * w2y[3];
    }
    for (; k < e; ++k) {
        int s0 = csrc[k];
        int a0 = ga[s0], b0 = gb[s0], c0 = gc[s0]; float4 i0 = I4[s0];
        float2 p0 = A2[(size_t)a0 * 32 + f2], q0 = B2[(size_t)b0 * 32 + f2],
               r0 = C2[(size_t)c0 * 32 + f2];
        ax += p0.x + q0.x + r0.x
            + i0.x * w2x[0] + i0.y * w2x[1] + i0.z * w2x[2] + i0.w * w2x[3];
        ay += p0.y + q0.y + r0.y
            + i0.x * w2y[0] + i0.y * w2y[1] + i0.z * w2y[2] + i0.w * w2y[3];
    }
    ((float2*)z)[(size_t)j * 32 + f2] = make_float2(fmaxf(ax, 0.f), fmaxf(ay, 0.f));
}

// -------- split segment sum
__global__ void segsum_split_k(const float* __restrict__ h, float* __restrict__ comb,
                               int per, int coloff, int S, int chunk) {
    int b = blockIdx.x;
    int g = b / S, s = b % S;
    int f = threadIdx.x;   // 64 threads
    int r0 = s * chunk;
    int r1 = min(per, r0 + chunk);
    float acc = 0.f;
    const float* p = h + ((size_t)g * per + r0) * HID + f;
    for (int r = r0; r < r1; ++r) { acc += *p; p += HID; }
    atomicAdd(&comb[g * 192 + coloff + f], acc);
}

// -------- classifier
__global__ void classifier_k(const float* __restrict__ comb,
                             const float* __restrict__ cW1, const float* __restrict__ cb1,
                             const float* __restrict__ cW2, const float* __restrict__ cb2,
                             float* __restrict__ out) {
    __shared__ float row[192];
    __shared__ float hid[64];
    int g = blockIdx.x, t = threadIdx.x;   // 64 threads
    for (int i = t; i < 192; i += 64) row[i] = comb[g * 192 + i];
    __syncthreads();
    float acc = cb1[t];
#pragma unroll 8
    for (int k = 0; k < 192; ++k) acc += row[k] * cW1[t * 192 + k];
    hid[t] = fmaxf(acc, 0.f);
    __syncthreads();
    if (t < 10) {
        float o = cb2[t];
#pragma unroll
        for (int k = 0; k < 64; ++k) o += hid[k] * cW2[t * 64 + k];
        out[g * 10 + t] = o;
    }
}

static inline int cdiv(long long a, long long b) { return (int)((a + b - 1) / b); }

extern "C" void kernel_launch(void* const* d_in, const int* in_sizes, int n_in,
                              void* d_out, int out_size, void* d_ws, size_t ws_size,
                              hipStream_t stream) {
    const float* x        = (const float*)d_in[0];
    const int*   eidx     = (const int*)d_in[1];
    const int*   gu2      = (const int*)d_in[3];
    const int*   gv2      = (const int*)d_in[4];
    const float* iso2     = (const float*)d_in[5];
    const int*   tedges   = (const int*)d_in[6];
    const int*   ga3      = (const int*)d_in[8];
    const int*   gb3      = (const int*)d_in[9];
    const int*   gc3      = (const int*)d_in[10];
    const float* iso3     = (const float*)d_in[11];
    const int*   hedges   = (const int*)d_in[12];
    const float* g1W1[3]  = {(const float*)d_in[14], (const float*)d_in[16], (const float*)d_in[18]};
    const float* g1W2[3]  = {(const float*)d_in[15], (const float*)d_in[17], (const float*)d_in[19]};
    const float* g2W1_0   = (const float*)d_in[20];
    const float* g2W2_0   = (const float*)d_in[21];
    const float* g2W1_1   = (const float*)d_in[22];
    const float* g2W2_1   = (const float*)d_in[23];
    const float* g3W1_0   = (const float*)d_in[24];
    const float* g3W2_0   = (const float*)d_in[25];
    const float* g3W1_1   = (const float*)d_in[26];
    const float* g3W2_1   = (const float*)d_in[27];
    const float* cW1      = (const float*)d_in[28];
    const float* cb1      = (const float*)d_in[29];
    const float* cW2      = (const float*)d_in[30];
    const float* cb2      = (const float*)d_in[31];
    float* out = (float*)d_out;

    const int N  = in_sizes[0] / 32;       // 2560
    const int E1 = in_sizes[1] / 2;
    const int n2 = in_sizes[3];            // 24320
    const int E2 = in_sizes[6] / 2;
    const int n3 = in_sizes[8];            // 145920
    const int E3 = in_sizes[12] / 2;
    const int G  = out_size / 10;          // 128
    const int per1 = N / G, per2 = n2 / G, per3 = n3 / G;

    // ---- workspace carve-up
    float* ws = (float*)d_ws;
    size_t off = 0;
    auto alloc = [&](size_t n) { float* p = ws + off; off += n; return p; };
    const size_t NH = (size_t)N * HID;
    float* nb0 = alloc(NH); float* nb1 = alloc(NH); float* nb2v = alloc(NH);
    float* hU1 = alloc(NH); float* hV1 = alloc(NH); float* hU2 = alloc(NH); float* hV2 = alloc(NH);
    float* hA1 = alloc(NH); float* hB1 = alloc(NH); float* hC1 = alloc(NH);
    float* hA2 = alloc(NH); float* hB2 = alloc(NH); float* hC2 = alloc(NH);
    float* z2 = alloc((size_t)n2 * HID); float* m2 = alloc((size_t)n2 * HID);
    float* z3 = alloc((size_t)n3 * HID); float* m3 = alloc((size_t)n3 * HID);
    float* comb = alloc((size_t)G * 192);
    // int workspace (CSR structures)
    int* iws = (int*)(ws + off);
    size_t ioff = 0;
    auto ialloc = [&](size_t n) { int* p = iws + ioff; ioff += n; return p; };
    int* rs1 = ialloc(N + 1);  int* cur1 = ialloc(N);  int* csrc1 = ialloc(E1);
    int* rs2 = ialloc(n2 + 1); int* cur2 = ialloc(n2); int* csrc2 = ialloc(E2);
    int* rs3 = ialloc(n3 + 1); int* cur3 = ialloc(n3); int* csrc3 = ialloc(E3);
    int* bsum1 = ialloc(256); int* bsum2 = ialloc(256); int* bsum3 = ialloc(256);
    (void)ws_size;

    dim3 B256(256);
    auto gemm2 = [&](const float* in, const float* Wa, const float* Wb,
                     float* oa, float* ob, int R, int K, int ldw, int coloff) {
        int waves = cdiv(R, RPW);
        int blocks = cdiv(waves, 4);
        if (K == 64)
            gemm2_reg<64><<<blocks, B256, 0, stream>>>(in, Wa, Wb, oa, ob, R, ldw, coloff);
        else
            gemm2_reg<32><<<blocks, B256, 0, stream>>>(in, Wa, Wb, oa, ob, R, ldw, coloff);
    };
    auto neigh = [&](const int* rs, const int* csrc, const float* m, float* z, int R) {
        int nb = cdiv(R, 8);
        int nb8 = cdiv(nb, 8);
        neighsum_relu_k<<<nb8 * 8, B256, 0, stream>>>(rs, csrc, m, z, R, nb8);
    };
    auto segsum = [&](const float* h, int per, int coloff) {
        int chunk = 64;
        int S = cdiv(per, chunk);
        segsum_split_k<<<G * S, 64, 0, stream>>>(h, comb, per, coloff, S, chunk);
    };

    // ---- batched CSR build (6 dispatches; comb zero folded into first)
    int nz1 = cdiv(N, 256), nz2 = cdiv(n2, 256), nz3 = cdiv(n3, 256), nz4 = cdiv(G * 192, 256);
    zero4_k<<<nz1 + nz2 + nz3 + nz4, B256, 0, stream>>>(
        cur1, N, cur2, n2, cur3, n3, (int*)comb, G * 192, nz1, nz2, nz3);
    int ne1 = cdiv(E1, 256), ne2 = cdiv(E2, 256), ne3 = cdiv(E3, 256);
    hist3_k<<<ne1 + ne2 + ne3, B256, 0, stream>>>(
        eidx, E1, cur1, tedges, E2, cur2, hedges, E3, cur3, ne1, ne2);
    int ns1 = cdiv(N + 1, 1024), ns2 = cdiv(n2 + 1, 1024), ns3 = cdiv(n3 + 1, 1024);
    scan1_3k<<<ns1 + ns2 + ns3, B256, 0, stream>>>(
        cur1, rs1, bsum1, N + 1, N, cur2, rs2, bsum2, n2 + 1, n2,
        cur3, rs3, bsum3, n3 + 1, n3, ns1, ns2);
    scan2_3k<<<1, B256, 0, stream>>>(bsum1, ns1, bsum2, ns2, bsum3, ns3);
    int nc1 = cdiv(N + 1, 256), nc2 = cdiv(n2 + 1, 256), nc3 = cdiv(n3 + 1, 256);
    scan3_3k<<<nc1 + nc2 + nc3, B256, 0, stream>>>(
        rs1, bsum1, N + 1, rs2, bsum2, n2 + 1, rs3, bsum3, n3 + 1, nc1, nc2);
    zero4_k<<<nz1 + nz2 + nz3, B256, 0, stream>>>(
        cur1, N, cur2, n2, cur3, n3, nullptr, 0, nz1, nz2, nz3);
    fill3_k<<<ne1 + ne2 + ne3, B256, 0, stream>>>(
        eidx, E1, rs1, cur1, csrc1, tedges, E2, rs2, cur2, csrc2,
        hedges, E3, rs3, cur3, csrc3, ne1, ne2);

    // ================= level 1: node GNN (3 layers) =================
    const float* hcur = x;
    float* bufs[3] = {nb0, nb1, nb2v};
    for (int l = 0; l < 3; ++l) {
        int K = (l == 0) ? 32 : 64;
        float* z = bufs[l % 3];
        float* m = bufs[(l + 1) % 3];
        gemm2(hcur, g1W1[l], g1W2[l], z, m, N, K, K, 0);
        neigh(rs1, csrc1, m, z, N);
        hcur = z;
    }
    const float* h = hcur;

    segsum(h, per1, 0);

    // ================= level 2: pair GNN (2 layers) =================
    gemm2(h, g2W1_0, g2W2_0, hU1, hU2, N, 64, 129, 0);
    gemm2(h, g2W1_0, g2W2_0, hV1, hV2, N, 64, 129, 64);
    {
        int nb = cdiv(n2, 8), nb8 = cdiv(nb, 8);
        neighsum0_l2_k<<<nb8 * 8, B256, 0, stream>>>(
            rs2, csrc2, hU1, hV1, hU2, hV2, gu2, gv2, iso2, g2W1_0, g2W2_0, z2, n2, nb8);
    }
    gemm2(z2, g2W1_1, g2W2_1, z2, m2, n2, 64, 64, 0);
    neigh(rs2, csrc2, m2, z2, n2);
    segsum(z2, per2, 64);

    // ================= level 3: triple GNN (2 layers) =================
    gemm2(h, g3W1_0, g3W2_0, hA1, hA2, N, 64, 196, 0);
    gemm2(h, g3W1_0, g3W2_0, hB1, hB2, N, 64, 196, 64);
    gemm2(h, g3W1_0, g3W2_0, hC1, hC2, N, 64, 196, 128);
    {
        int nb = cdiv(n3, 8), nb8 = cdiv(nb, 8);
        neighsum0_l3_k<<<nb8 * 8, B256, 0, stream>>>(
            rs3, csrc3, hA1, hB1, hC1, hA2, hB2, hC2, ga3, gb3, gc3, iso3,
            g3W1_0, g3W2_0, z3, n3, nb8);
    }
    gemm2(z3, g3W1_1, g3W2_1, z3, m3, n3, 64, 64, 0);
    neigh(rs3, csrc3, m3, z3, n3);
    segsum(z3, per3, 128);

    // ================= classifier =================
    classifier_k<<<G, 64, 0, stream>>>(comb, cW1, cb1, cW2, cb2, out);
}

// Round 12
// 575.906 us; speedup vs baseline: 1.1181x; 1.1181x over previous
//
#include <hip/hip_runtime.h>
#include <hip/hip_bf16.h>

#define HID 64
#define RPW 16   // rows per wave in gemm2_reg
#define KCH 8    // k-chunk width (W regs live at a time = 2*KCH)

// -------- fused dual GEMM, K-chunked register tiling, SCALAR row broadcast.
// (R10 version, unchanged: 55us on n3, at its in-place ~2TB/s point.)
template <int KC>
__global__ __attribute__((amdgpu_flat_work_group_size(256, 256),
                          amdgpu_waves_per_eu(6, 6)))
void gemm2_reg(const float* in,
               const float* __restrict__ Wa, const float* __restrict__ Wb,
               float* outa, float* outb,
               int R, int ldw, int coloff) {
    int lane = threadIdx.x & 63;
    int wid = blockIdx.x * (blockDim.x >> 6) + (threadIdx.x >> 6);
    int j0 = __builtin_amdgcn_readfirstlane(wid * RPW);
    if (j0 >= R) return;                       // uniform branch
    float accx[RPW], accy[RPW];
#pragma unroll
    for (int r = 0; r < RPW; ++r) { accx[r] = 0.f; accy[r] = 0.f; }
    const float* pa = Wa + (size_t)lane * ldw + coloff;
    const float* pb = Wb + (size_t)lane * ldw + coloff;
#pragma unroll 1
    for (int kc = 0; kc < KC; kc += KCH) {
        float wx[KCH], wy[KCH];
#pragma unroll
        for (int kk = 0; kk < KCH; ++kk) { wx[kk] = pa[kc + kk]; wy[kk] = pb[kc + kk]; }
#pragma unroll
        for (int r = 0; r < RPW; ++r) {
            const float* rp = in + (size_t)(j0 + r) * KC + kc;   // uniform ptr
#pragma unroll
            for (int kk = 0; kk < KCH; ++kk) {
                float s = rp[kk];              // uniform load -> s_load
                accx[r] = fmaf(s, wx[kk], accx[r]);
                accy[r] = fmaf(s, wy[kk], accy[r]);
            }
        }
    }
#pragma unroll
    for (int r = 0; r < RPW; ++r) {
        int j = j0 + r;
        outa[(size_t)j * HID + lane] = accx[r];
        outb[(size_t)j * HID + lane] = accy[r];
    }
}

// ======== batched CSR build: each stage covers all 3 edge sets ========
__global__ void zero4_k(int* p1, int s1, int* p2, int s2, int* p3, int s3,
                        int* p4, int s4, int nb1, int nb2, int nb3) {
    int b = blockIdx.x; int* p; int n; int lb;
    if (b < nb1)                 { p = p1; n = s1; lb = b; }
    else if (b < nb1 + nb2)      { p = p2; n = s2; lb = b - nb1; }
    else if (b < nb1 + nb2 + nb3){ p = p3; n = s3; lb = b - nb1 - nb2; }
    else                         { p = p4; n = s4; lb = b - nb1 - nb2 - nb3; }
    int i = lb * 256 + threadIdx.x;
    if (i < n) p[i] = 0;
}

__global__ void hist3_k(const int* e1, int E1, int* c1,
                        const int* e2, int E2, int* c2,
                        const int* e3, int E3, int* c3, int nb1, int nb2) {
    int b = blockIdx.x; const int* dst; int* c; int E; int lb;
    if (b < nb1)            { dst = e1 + E1; c = c1; E = E1; lb = b; }
    else if (b < nb1 + nb2) { dst = e2 + E2; c = c2; E = E2; lb = b - nb1; }
    else                    { dst = e3 + E3; c = c3; E = E3; lb = b - nb1 - nb2; }
    int e = lb * 256 + threadIdx.x;
    if (e < E) atomicAdd(&c[dst[e]], 1);
}

__device__ __forceinline__ void scan1_body(const int* __restrict__ cnt, int* __restrict__ rs,
                                           int* __restrict__ bsum, int n1, int n, int lb) {
    __shared__ int wsum[4];
    int t = threadIdx.x;
    int base = lb * 1024 + t * 4;
    int v[4]; int s = 0;
#pragma unroll
    for (int i = 0; i < 4; ++i) { int idx = base + i; v[i] = s; s += (idx < n) ? cnt[idx] : 0; }
    int lane = t & 63, wv = t >> 6;
    int x = s;
#pragma unroll
    for (int off = 1; off < 64; off <<= 1) { int y = __shfl_up(x, off, 64); if (lane >= off) x += y; }
    if (lane == 63) wsum[wv] = x;
    __syncthreads();
    int woff = 0;
    for (int w = 0; w < wv; ++w) woff += wsum[w];
    int excl = woff + (x - s);
#pragma unroll
    for (int i = 0; i < 4; ++i) { int idx = base + i; if (idx < n1) rs[idx] = excl + v[i]; }
    if (t == 255) bsum[lb] = wsum[0] + wsum[1] + wsum[2] + wsum[3];
}

__global__ void scan1_3k(const int* c1, int* r1, int* b1, int n1a, int na,
                         const int* c2, int* r2, int* b2, int n1b, int nb,
                         const int* c3, int* r3, int* b3, int n1c, int nc,
                         int nbl1, int nbl2) {
    int b = blockIdx.x;
    if (b < nbl1)             scan1_body(c1, r1, b1, n1a, na, b);
    else if (b < nbl1 + nbl2) scan1_body(c2, r2, b2, n1b, nb, b - nbl1);
    else                      scan1_body(c3, r3, b3, n1c, nc, b - nbl1 - nbl2);
}

__device__ __forceinline__ void scan2_body(int* bsum, int nb, int* wsum) {
    int t = threadIdx.x;
    int s = (t < nb) ? bsum[t] : 0;
    int lane = t & 63, wv = t >> 6;
    int x = s;
#pragma unroll
    for (int off = 1; off < 64; off <<= 1) { int y = __shfl_up(x, off, 64); if (lane >= off) x += y; }
    if (lane == 63) wsum[wv] = x;
    __syncthreads();
    int woff = 0;
    for (int w = 0; w < wv; ++w) woff += wsum[w];
    if (t < nb) bsum[t] = woff + x - s;   // exclusive
    __syncthreads();                       // before wsum reuse
}

__global__ void scan2_3k(int* b1, int nb1, int* b2, int nb2, int* b3, int nb3) {
    __shared__ int wsum[4];
    scan2_body(b1, nb1, wsum);
    scan2_body(b2, nb2, wsum);
    scan2_body(b3, nb3, wsum);
}

__global__ void scan3_3k(int* r1, const int* b1, int n1a,
                         int* r2, const int* b2, int n1b,
                         int* r3, const int* b3, int n1c, int nc1, int nc2) {
    int b = blockIdx.x; int* rs; const int* bsum; int n1; int lb;
    if (b < nc1)            { rs = r1; bsum = b1; n1 = n1a; lb = b; }
    else if (b < nc1 + nc2) { rs = r2; bsum = b2; n1 = n1b; lb = b - nc1; }
    else                    { rs = r3; bsum = b3; n1 = n1c; lb = b - nc1 - nc2; }
    int i = lb * 256 + threadIdx.x;
    if (i < n1) rs[i] += bsum[lb >> 2];
}

__global__ void fill3_k(const int* e1, int E1, const int* r1, int* c1, int* s1,
                        const int* e2, int E2, const int* r2, int* c2, int* s2,
                        const int* e3, int E3, const int* r3, int* c3, int* s3,
                        int nb1, int nb2) {
    int b = blockIdx.x;
    const int* edges; int E; const int* rs; int* cur; int* csrc; int lb;
    if (b < nb1)            { edges = e1; E = E1; rs = r1; cur = c1; csrc = s1; lb = b; }
    else if (b < nb1 + nb2) { edges = e2; E = E2; rs = r2; cur = c2; csrc = s2; lb = b - nb1; }
    else                    { edges = e3; E = E3; rs = r3; cur = c3; csrc = s3; lb = b - nb1 - nb2; }
    int e = lb * 256 + threadIdx.x;
    if (e >= E) return;
    int d = edges[E + e];
    int p = rs[d] + atomicAdd(&cur[d], 1);
    csrc[p] = edges[e];
}

// -------- plain gather + relu (layer 1 of each level)
__global__ void neighsum_relu_k(const int* __restrict__ rs, const int* __restrict__ csrc,
                                const float* __restrict__ m, float* __restrict__ z,
                                int R, int nb8) {
    int b = (int)(blockIdx.x & 7) * nb8 + (int)(blockIdx.x >> 3);
    int t = threadIdx.x;
    int wv = t >> 6, lane = t & 63;
    int j = b * 8 + wv * 2 + (lane >> 5);   // 8 rows per block
    int f2 = lane & 31;
    if (j >= R) return;
    const float2* m2 = (const float2*)m;
    float2* z2p = (float2*)z;
    int s = rs[j], e = rs[j + 1];
    float2 a = z2p[(size_t)j * 32 + f2];
    float ax = a.x, ay = a.y;
    int k = s;
    for (; k + 8 <= e; k += 8) {
        int i0 = csrc[k],     i1 = csrc[k + 1], i2 = csrc[k + 2], i3 = csrc[k + 3];
        int i4 = csrc[k + 4], i5 = csrc[k + 5], i6 = csrc[k + 6], i7 = csrc[k + 7];
        float2 v0 = m2[(size_t)i0 * 32 + f2], v1 = m2[(size_t)i1 * 32 + f2];
        float2 v2 = m2[(size_t)i2 * 32 + f2], v3 = m2[(size_t)i3 * 32 + f2];
        float2 v4 = m2[(size_t)i4 * 32 + f2], v5 = m2[(size_t)i5 * 32 + f2];
        float2 v6 = m2[(size_t)i6 * 32 + f2], v7 = m2[(size_t)i7 * 32 + f2];
        ax += ((v0.x + v1.x) + (v2.x + v3.x)) + ((v4.x + v5.x) + (v6.x + v7.x));
        ay += ((v0.y + v1.y) + (v2.y + v3.y)) + ((v4.y + v5.y) + (v6.y + v7.y));
    }
    for (; k + 4 <= e; k += 4) {
        int i0 = csrc[k], i1 = csrc[k + 1], i2 = csrc[k + 2], i3 = csrc[k + 3];
        float2 v0 = m2[(size_t)i0 * 32 + f2], v1 = m2[(size_t)i1 * 32 + f2];
        float2 v2 = m2[(size_t)i2 * 32 + f2], v3 = m2[(size_t)i3 * 32 + f2];
        ax += (v0.x + v1.x) + (v2.x + v3.x);
        ay += (v0.y + v1.y) + (v2.y + v3.y);
    }
    for (; k < e; ++k) {
        float2 v = m2[(size_t)csrc[k] * 32 + f2];
        ax += v.x; ay += v.y;
    }
    z2p[(size_t)j * 32 + f2] = make_float2(fmaxf(ax, 0.f), fmaxf(ay, 0.f));
}

// -------- materialize level-2 layer-0 messages ONLY:
// m2[j] = hU2[gu[j]] + hV2[gv[j]] + iso2[j]*W2[:,128]
__global__ void gatherM2_k(const float* __restrict__ hU2, const float* __restrict__ hV2,
                           const int* __restrict__ gu, const int* __restrict__ gv,
                           const float* __restrict__ iso2, const float* __restrict__ W2,
                           float* __restrict__ m2, int n2) {
    int idx = blockIdx.x * blockDim.x + threadIdx.x;
    int j = idx >> 6, f = idx & 63;
    if (j >= n2) return;
    int u = gu[j], v = gv[j];
    m2[idx] = hU2[u * HID + f] + hV2[v * HID + f] + iso2[j] * W2[f * 129 + 128];
}

// -------- level-2 layer-0 neighbor sum with FUSED ROW INIT (per-row, cheap):
// z2[j] = relu(hU1[gu[j]] + hV1[gv[j]] + iso2[j]*W1[:,128] + sum_s m2[s])
// Per-edge cost stays 1 gather (R11 lesson: inlining messages per-edge = 3x
// dependent table gathers -> 176us L2-latency bound; materialized m = ~30us).
__global__ void neighsum0i_l2_k(const int* __restrict__ rs, const int* __restrict__ csrc,
                                const float* __restrict__ m,
                                const float* __restrict__ hU1, const float* __restrict__ hV1,
                                const int* __restrict__ gu, const int* __restrict__ gv,
                                const float* __restrict__ iso2, const float* __restrict__ W1,
                                float* __restrict__ z, int R, int nb8) {
    int b = (int)(blockIdx.x & 7) * nb8 + (int)(blockIdx.x >> 3);
    int t = threadIdx.x;
    int wv = t >> 6, lane = t & 63;
    int j = b * 8 + wv * 2 + (lane >> 5);
    int f2 = lane & 31;
    if (j >= R) return;
    const float2* m2 = (const float2*)m;
    const float2* U1 = (const float2*)hU1; const float2* V1 = (const float2*)hV1;
    int uj = gu[j], vj = gv[j];
    float isj = iso2[j];
    float2 vu = U1[(size_t)uj * 32 + f2], vv = V1[(size_t)vj * 32 + f2];
    float ax = vu.x + vv.x + isj * W1[(2 * f2) * 129 + 128];
    float ay = vu.y + vv.y + isj * W1[(2 * f2 + 1) * 129 + 128];
    int s = rs[j], e = rs[j + 1];
    int k = s;
    for (; k + 8 <= e; k += 8) {
        int i0 = csrc[k],     i1 = csrc[k + 1], i2 = csrc[k + 2], i3 = csrc[k + 3];
        int i4 = csrc[k + 4], i5 = csrc[k + 5], i6 = csrc[k + 6], i7 = csrc[k + 7];
        float2 v0 = m2[(size_t)i0 * 32 + f2], v1 = m2[(size_t)i1 * 32 + f2];
        float2 v2 = m2[(size_t)i2 * 32 + f2], v3 = m2[(size_t)i3 * 32 + f2];
        float2 v4 = m2[(size_t)i4 * 32 + f2], v5 = m2[(size_t)i5 * 32 + f2];
        float2 v6 = m2[(size_t)i6 * 32 + f2], v7 = m2[(size_t)i7 * 32 + f2];
        ax += ((v0.x + v1.x) + (v2.x + v3.x)) + ((v4.x + v5.x) + (v6.x + v7.x));
        ay += ((v0.y + v1.y) + (v2.y + v3.y)) + ((v4.y + v5.y) + (v6.y + v7.y));
    }
    for (; k + 4 <= e; k += 4) {
        int i0 = csrc[k], i1 = csrc[k + 1], i2 = csrc[k + 2], i3 = csrc[k + 3];
        float2 v0 = m2[(size_t)i0 * 32 + f2], v1 = m2[(size_t)i1 * 32 + f2];
        float2 v2 = m2[(size_t)i2 * 32 + f2], v3 = m2[(size_t)i3 * 32 + f2];
        ax += (v0.x + v1.x) + (v2.x + v3.x);
        ay += (v0.y + v1.y) + (v2.y + v3.y);
    }
    for (; k < e; ++k) {
        float2 v = m2[(size_t)csrc[k] * 32 + f2];
        ax += v.x; ay += v.y;
    }
    ((float2*)z)[(size_t)j * 32 + f2] = make_float2(fmaxf(ax, 0.f), fmaxf(ay, 0.f));
}

// -------- materialize level-3 layer-0 messages ONLY (iso3 one-hot x4)
__global__ void gatherM3_k(const float* __restrict__ hA2, const float* __restrict__ hB2,
                           const float* __restrict__ hC2,
                           const int* __restrict__ ga, const int* __restrict__ gb,
                           const int* __restrict__ gc, const float* __restrict__ iso3,
                           const float* __restrict__ W2,
                           float* __restrict__ m3, int n3) {
    int idx = blockIdx.x * blockDim.x + threadIdx.x;
    int j = idx >> 6, f = idx & 63;
    if (j >= n3) return;
    int a = ga[j], b = gb[j], c = gc[j];
    float i0 = iso3[j * 4 + 0], i1 = iso3[j * 4 + 1], i2 = iso3[j * 4 + 2], i3 = iso3[j * 4 + 3];
    float m = hA2[a * HID + f] + hB2[b * HID + f] + hC2[c * HID + f];
    m += i0 * W2[f * 196 + 192] + i1 * W2[f * 196 + 193]
       + i2 * W2[f * 196 + 194] + i3 * W2[f * 196 + 195];
    m3[idx] = m;
}

// -------- level-3 layer-0 neighbor sum with FUSED ROW INIT
__global__ void neighsum0i_l3_k(const int* __restrict__ rs, const int* __restrict__ csrc,
                                const float* __restrict__ m,
                                const float* __restrict__ hA1, const float* __restrict__ hB1,
                                const float* __restrict__ hC1,
                                const int* __restrict__ ga, const int* __restrict__ gb,
                                const int* __restrict__ gc, const float* __restrict__ iso3,
                                const float* __restrict__ W1,
                                float* __restrict__ z, int R, int nb8) {
    int b = (int)(blockIdx.x & 7) * nb8 + (int)(blockIdx.x >> 3);
    int t = threadIdx.x;
    int wv = t >> 6, lane = t & 63;
    int j = b * 8 + wv * 2 + (lane >> 5);
    int f2 = lane & 31;
    if (j >= R) return;
    const float2* m2 = (const float2*)m;
    const float2* A1 = (const float2*)hA1; const float2* B1 = (const float2*)hB1;
    const float2* C1 = (const float2*)hC1;
    const float4* I4 = (const float4*)iso3;
    int aj = ga[j], bj = gb[j], cj = gc[j];
    float4 ij = I4[j];
    float2 va = A1[(size_t)aj * 32 + f2], vb = B1[(size_t)bj * 32 + f2],
           vc = C1[(size_t)cj * 32 + f2];
    int r1x = (2 * f2) * 196 + 192, r1y = (2 * f2 + 1) * 196 + 192;
    float ax = va.x + vb.x + vc.x
             + ij.x * W1[r1x] + ij.y * W1[r1x + 1] + ij.z * W1[r1x + 2] + ij.w * W1[r1x + 3];
    float ay = va.y + vb.y + vc.y
             + ij.x * W1[r1y] + ij.y * W1[r1y + 1] + ij.z * W1[r1y + 2] + ij.w * W1[r1y + 3];
    int s = rs[j], e = rs[j + 1];
    int k = s;
    for (; k + 8 <= e; k += 8) {
        int i0 = csrc[k],     i1 = csrc[k + 1], i2 = csrc[k + 2], i3 = csrc[k + 3];
        int i4 = csrc[k + 4], i5 = csrc[k + 5], i6 = csrc[k + 6], i7 = csrc[k + 7];
        float2 v0 = m2[(size_t)i0 * 32 + f2], v1 = m2[(size_t)i1 * 32 + f2];
        float2 v2 = m2[(size_t)i2 * 32 + f2], v3 = m2[(size_t)i3 * 32 + f2];
        float2 v4 = m2[(size_t)i4 * 32 + f2], v5 = m2[(size_t)i5 * 32 + f2];
        float2 v6 = m2[(size_t)i6 * 32 + f2], v7 = m2[(size_t)i7 * 32 + f2];
        ax += ((v0.x + v1.x) + (v2.x + v3.x)) + ((v4.x + v5.x) + (v6.x + v7.x));
        ay += ((v0.y + v1.y) + (v2.y + v3.y)) + ((v4.y + v5.y) + (v6.y + v7.y));
    }
    for (; k + 4 <= e; k += 4) {
        int i0 = csrc[k], i1 = csrc[k + 1], i2 = csrc[k + 2], i3 = csrc[k + 3];
        float2 v0 = m2[(size_t)i0 * 32 + f2], v1 = m2[(size_t)i1 * 32 + f2];
        float2 v2 = m2[(size_t)i2 * 32 + f2], v3 = m2[(size_t)i3 * 32 + f2];
        ax += (v0.x + v1.x) + (v2.x + v3.x);
        ay += (v0.y + v1.y) + (v2.y + v3.y);
    }
    for (; k < e; ++k) {
        float2 v = m2[(size_t)csrc[k] * 32 + f2];
        ax += v.x; ay += v.y;
    }
    ((float2*)z)[(size_t)j * 32 + f2] = make_float2(fmaxf(ax, 0.f), fmaxf(ay, 0.f));
}

// -------- split segment sum
__global__ void segsum_split_k(const float* __restrict__ h, float* __restrict__ comb,
                               int per, int coloff, int S, int chunk) {
    int b = blockIdx.x;
    int g = b / S, s = b % S;
    int f = threadIdx.x;   // 64 threads
    int r0 = s * chunk;
    int r1 = min(per, r0 + chunk);
    float acc = 0.f;
    const float* p = h + ((size_t)g * per + r0) * HID + f;
    for (int r = r0; r < r1; ++r) { acc += *p; p += HID; }
    atomicAdd(&comb[g * 192 + coloff + f], acc);
}

// -------- classifier
__global__ void classifier_k(const float* __restrict__ comb,
                             const float* __restrict__ cW1, const float* __restrict__ cb1,
                             const float* __restrict__ cW2, const float* __restrict__ cb2,
                             float* __restrict__ out) {
    __shared__ float row[192];
    __shared__ float hid[64];
    int g = blockIdx.x, t = threadIdx.x;   // 64 threads
    for (int i = t; i < 192; i += 64) row[i] = comb[g * 192 + i];
    __syncthreads();
    float acc = cb1[t];
#pragma unroll 8
    for (int k = 0; k < 192; ++k) acc += row[k] * cW1[t * 192 + k];
    hid[t] = fmaxf(acc, 0.f);
    __syncthreads();
    if (t < 10) {
        float o = cb2[t];
#pragma unroll
        for (int k = 0; k < 64; ++k) o += hid[k] * cW2[t * 64 + k];
        out[g * 10 + t] = o;
    }
}

static inline int cdiv(long long a, long long b) { return (int)((a + b - 1) / b); }

extern "C" void kernel_launch(void* const* d_in, const int* in_sizes, int n_in,
                              void* d_out, int out_size, void* d_ws, size_t ws_size,
                              hipStream_t stream) {
    const float* x        = (const float*)d_in[0];
    const int*   eidx     = (const int*)d_in[1];
    const int*   gu2      = (const int*)d_in[3];
    const int*   gv2      = (const int*)d_in[4];
    const float* iso2     = (const float*)d_in[5];
    const int*   tedges   = (const int*)d_in[6];
    const int*   ga3      = (const int*)d_in[8];
    const int*   gb3      = (const int*)d_in[9];
    const int*   gc3      = (const int*)d_in[10];
    const float* iso3     = (const float*)d_in[11];
    const int*   hedges   = (const int*)d_in[12];
    const float* g1W1[3]  = {(const float*)d_in[14], (const float*)d_in[16], (const float*)d_in[18]};
    const float* g1W2[3]  = {(const float*)d_in[15], (const float*)d_in[17], (const float*)d_in[19]};
    const float* g2W1_0   = (const float*)d_in[20];
    const float* g2W2_0   = (const float*)d_in[21];
    const float* g2W1_1   = (const float*)d_in[22];
    const float* g2W2_1   = (const float*)d_in[23];
    const float* g3W1_0   = (const float*)d_in[24];
    const float* g3W2_0   = (const float*)d_in[25];
    const float* g3W1_1   = (const float*)d_in[26];
    const float* g3W2_1   = (const float*)d_in[27];
    const float* cW1      = (const float*)d_in[28];
    const float* cb1      = (const float*)d_in[29];
    const float* cW2      = (const float*)d_in[30];
    const float* cb2      = (const float*)d_in[31];
    float* out = (float*)d_out;

    const int N  = in_sizes[0] / 32;       // 2560
    const int E1 = in_sizes[1] / 2;
    const int n2 = in_sizes[3];            // 24320
    const int E2 = in_sizes[6] / 2;
    const int n3 = in_sizes[8];            // 145920
    const int E3 = in_sizes[12] / 2;
    const int G  = out_size / 10;          // 128
    const int per1 = N / G, per2 = n2 / G, per3 = n3 / G;

    // ---- workspace carve-up
    float* ws = (float*)d_ws;
    size_t off = 0;
    auto alloc = [&](size_t n) { float* p = ws + off; off += n; return p; };
    const size_t NH = (size_t)N * HID;
    float* nb0 = alloc(NH); float* nb1 = alloc(NH); float* nb2v = alloc(NH);
    float* hU1 = alloc(NH); float* hV1 = alloc(NH); float* hU2 = alloc(NH); float* hV2 = alloc(NH);
    float* hA1 = alloc(NH); float* hB1 = alloc(NH); float* hC1 = alloc(NH);
    float* hA2 = alloc(NH); float* hB2 = alloc(NH); float* hC2 = alloc(NH);
    float* z2 = alloc((size_t)n2 * HID); float* m2 = alloc((size_t)n2 * HID);
    float* z3 = alloc((size_t)n3 * HID); float* m3 = alloc((size_t)n3 * HID);
    float* comb = alloc((size_t)G * 192);
    // int workspace (CSR structures)
    int* iws = (int*)(ws + off);
    size_t ioff = 0;
    auto ialloc = [&](size_t n) { int* p = iws + ioff; ioff += n; return p; };
    int* rs1 = ialloc(N + 1);  int* cur1 = ialloc(N);  int* csrc1 = ialloc(E1);
    int* rs2 = ialloc(n2 + 1); int* cur2 = ialloc(n2); int* csrc2 = ialloc(E2);
    int* rs3 = ialloc(n3 + 1); int* cur3 = ialloc(n3); int* csrc3 = ialloc(E3);
    int* bsum1 = ialloc(256); int* bsum2 = ialloc(256); int* bsum3 = ialloc(256);
    (void)ws_size;

    dim3 B256(256);
    auto gemm2 = [&](const float* in, const float* Wa, const float* Wb,
                     float* oa, float* ob, int R, int K, int ldw, int coloff) {
        int waves = cdiv(R, RPW);
        int blocks = cdiv(waves, 4);
        if (K == 64)
            gemm2_reg<64><<<blocks, B256, 0, stream>>>(in, Wa, Wb, oa, ob, R, ldw, coloff);
        else
            gemm2_reg<32><<<blocks, B256, 0, stream>>>(in, Wa, Wb, oa, ob, R, ldw, coloff);
    };
    auto neigh = [&](const int* rs, const int* csrc, const float* m, float* z, int R) {
        int nb = cdiv(R, 8);
        int nb8 = cdiv(nb, 8);
        neighsum_relu_k<<<nb8 * 8, B256, 0, stream>>>(rs, csrc, m, z, R, nb8);
    };
    auto segsum = [&](const float* h, int per, int coloff) {
        int chunk = 64;
        int S = cdiv(per, chunk);
        segsum_split_k<<<G * S, 64, 0, stream>>>(h, comb, per, coloff, S, chunk);
    };

    // ---- batched CSR build (7 dispatches; comb zero folded into first)
    int nz1 = cdiv(N, 256), nz2 = cdiv(n2, 256), nz3 = cdiv(n3, 256), nz4 = cdiv(G * 192, 256);
    zero4_k<<<nz1 + nz2 + nz3 + nz4, B256, 0, stream>>>(
        cur1, N, cur2, n2, cur3, n3, (int*)comb, G * 192, nz1, nz2, nz3);
    int ne1 = cdiv(E1, 256), ne2 = cdiv(E2, 256), ne3 = cdiv(E3, 256);
    hist3_k<<<ne1 + ne2 + ne3, B256, 0, stream>>>(
        eidx, E1, cur1, tedges, E2, cur2, hedges, E3, cur3, ne1, ne2);
    int ns1 = cdiv(N + 1, 1024), ns2 = cdiv(n2 + 1, 1024), ns3 = cdiv(n3 + 1, 1024);
    scan1_3k<<<ns1 + ns2 + ns3, B256, 0, stream>>>(
        cur1, rs1, bsum1, N + 1, N, cur2, rs2, bsum2, n2 + 1, n2,
        cur3, rs3, bsum3, n3 + 1, n3, ns1, ns2);
    scan2_3k<<<1, B256, 0, stream>>>(bsum1, ns1, bsum2, ns2, bsum3, ns3);
    int nc1 = cdiv(N + 1, 256), nc2 = cdiv(n2 + 1, 256), nc3 = cdiv(n3 + 1, 256);
    scan3_3k<<<nc1 + nc2 + nc3, B256, 0, stream>>>(
        rs1, bsum1, N + 1, rs2, bsum2, n2 + 1, rs3, bsum3, n3 + 1, nc1, nc2);
    zero4_k<<<nz1 + nz2 + nz3, B256, 0, stream>>>(
        cur1, N, cur2, n2, cur3, n3, nullptr, 0, nz1, nz2, nz3);
    fill3_k<<<ne1 + ne2 + ne3, B256, 0, stream>>>(
        eidx, E1, rs1, cur1, csrc1, tedges, E2, rs2, cur2, csrc2,
        hedges, E3, rs3, cur3, csrc3, ne1, ne2);

    // ================= level 1: node GNN (3 layers) =================
    const float* hcur = x;
    float* bufs[3] = {nb0, nb1, nb2v};
    for (int l = 0; l < 3; ++l) {
        int K = (l == 0) ? 32 : 64;
        float* z = bufs[l % 3];
        float* m = bufs[(l + 1) % 3];
        gemm2(hcur, g1W1[l], g1W2[l], z, m, N, K, K, 0);
        neigh(rs1, csrc1, m, z, N);
        hcur = z;
    }
    const float* h = hcur;

    segsum(h, per1, 0);

    // ================= level 2: pair GNN (2 layers) =================
    gemm2(h, g2W1_0, g2W2_0, hU1, hU2, N, 64, 129, 0);
    gemm2(h, g2W1_0, g2W2_0, hV1, hV2, N, 64, 129, 64);
    gatherM2_k<<<cdiv((long long)n2 * 64, 256), B256, 0, stream>>>(
        hU2, hV2, gu2, gv2, iso2, g2W2_0, m2, n2);
    {
        int nb = cdiv(n2, 8), nb8 = cdiv(nb, 8);
        neighsum0i_l2_k<<<nb8 * 8, B256, 0, stream>>>(
            rs2, csrc2, m2, hU1, hV1, gu2, gv2, iso2, g2W1_0, z2, n2, nb8);
    }
    gemm2(z2, g2W1_1, g2W2_1, z2, m2, n2, 64, 64, 0);
    neigh(rs2, csrc2, m2, z2, n2);
    segsum(z2, per2, 64);

    // ================= level 3: triple GNN (2 layers) =================
    gemm2(h, g3W1_0, g3W2_0, hA1, hA2, N, 64, 196, 0);
    gemm2(h, g3W1_0, g3W2_0, hB1, hB2, N, 64, 196, 64);
    gemm2(h, g3W1_0, g3W2_0, hC1, hC2, N, 64, 196, 128);
    gatherM3_k<<<cdiv((long long)n3 * 64, 256), B256, 0, stream>>>(
        hA2, hB2, hC2, ga3, gb3, gc3, iso3, g3W2_0, m3, n3);
    {
        int nb = cdiv(n3, 8), nb8 = cdiv(nb, 8);
        neighsum0i_l3_k<<<nb8 * 8, B256, 0, stream>>>(
            rs3, csrc3, m3, hA1, hB1, hC1, ga3, gb3, gc3, iso3, g3W1_0, z3, n3, nb8);
    }
    gemm2(z3, g3W1_1, g3W2_1, z3, m3, n3, 64, 64, 0);
    neigh(rs3, csrc3, m3, z3, n3);
    segsum(z3, per3, 128);

    // ================= classifier =================
    classifier_k<<<G, 64, 0, stream>>>(comb, cW1, cb1, cW2, cb2, out);
}

// Round 13
// 541.901 us; speedup vs baseline: 1.1882x; 1.0627x over previous
//
#include <hip/hip_runtime.h>
#include <hip/hip_bf16.h>

#define HID 64
#define RPW 16   // rows per wave in gemm2_reg
#define KCH 8    // k-chunk width (W regs live at a time = 2*KCH)

typedef __hip_bfloat16  bf16;
typedef __hip_bfloat162 bf162;
__device__ __forceinline__ float bl(bf16 h) { return __bfloat162float(h); }

// -------- fused dual GEMM, fp32 outputs (table production). R10 version.
template <int KC>
__global__ __attribute__((amdgpu_flat_work_group_size(256, 256),
                          amdgpu_waves_per_eu(6, 6)))
void gemm2_reg(const float* in,
               const float* __restrict__ Wa, const float* __restrict__ Wb,
               float* outa, float* outb,
               int R, int ldw, int coloff) {
    int lane = threadIdx.x & 63;
    int wid = blockIdx.x * (blockDim.x >> 6) + (threadIdx.x >> 6);
    int j0 = __builtin_amdgcn_readfirstlane(wid * RPW);
    if (j0 >= R) return;
    float accx[RPW], accy[RPW];
#pragma unroll
    for (int r = 0; r < RPW; ++r) { accx[r] = 0.f; accy[r] = 0.f; }
    const float* pa = Wa + (size_t)lane * ldw + coloff;
    const float* pb = Wb + (size_t)lane * ldw + coloff;
#pragma unroll 1
    for (int kc = 0; kc < KC; kc += KCH) {
        float wx[KCH], wy[KCH];
#pragma unroll
        for (int kk = 0; kk < KCH; ++kk) { wx[kk] = pa[kc + kk]; wy[kk] = pb[kc + kk]; }
#pragma unroll
        for (int r = 0; r < RPW; ++r) {
            const float* rp = in + (size_t)(j0 + r) * KC + kc;
#pragma unroll
            for (int kk = 0; kk < KCH; ++kk) {
                float s = rp[kk];
                accx[r] = fmaf(s, wx[kk], accx[r]);
                accy[r] = fmaf(s, wy[kk], accy[r]);
            }
        }
    }
#pragma unroll
    for (int r = 0; r < RPW; ++r) {
        int j = j0 + r;
        outa[(size_t)j * HID + lane] = accx[r];
        outb[(size_t)j * HID + lane] = accy[r];
    }
}

// -------- same, but outb (the message operand) stored as bf16.
template <int KC>
__global__ __attribute__((amdgpu_flat_work_group_size(256, 256),
                          amdgpu_waves_per_eu(6, 6)))
void gemm2_regb(const float* in,
                const float* __restrict__ Wa, const float* __restrict__ Wb,
                float* outa, bf16* outb,
                int R, int ldw, int coloff) {
    int lane = threadIdx.x & 63;
    int wid = blockIdx.x * (blockDim.x >> 6) + (threadIdx.x >> 6);
    int j0 = __builtin_amdgcn_readfirstlane(wid * RPW);
    if (j0 >= R) return;
    float accx[RPW], accy[RPW];
#pragma unroll
    for (int r = 0; r < RPW; ++r) { accx[r] = 0.f; accy[r] = 0.f; }
    const float* pa = Wa + (size_t)lane * ldw + coloff;
    const float* pb = Wb + (size_t)lane * ldw + coloff;
#pragma unroll 1
    for (int kc = 0; kc < KC; kc += KCH) {
        float wx[KCH], wy[KCH];
#pragma unroll
        for (int kk = 0; kk < KCH; ++kk) { wx[kk] = pa[kc + kk]; wy[kk] = pb[kc + kk]; }
#pragma unroll
        for (int r = 0; r < RPW; ++r) {
            const float* rp = in + (size_t)(j0 + r) * KC + kc;
#pragma unroll
            for (int kk = 0; kk < KCH; ++kk) {
                float s = rp[kk];
                accx[r] = fmaf(s, wx[kk], accx[r]);
                accy[r] = fmaf(s, wy[kk], accy[r]);
            }
        }
    }
#pragma unroll
    for (int r = 0; r < RPW; ++r) {
        int j = j0 + r;
        outa[(size_t)j * HID + lane] = accx[r];
        outb[(size_t)j * HID + lane] = __float2bfloat16(accy[r]);
    }
}

// ======== batched CSR build (R12, unchanged) ========
__global__ void zero4_k(int* p1, int s1, int* p2, int s2, int* p3, int s3,
                        int* p4, int s4, int nb1, int nb2, int nb3) {
    int b = blockIdx.x; int* p; int n; int lb;
    if (b < nb1)                 { p = p1; n = s1; lb = b; }
    else if (b < nb1 + nb2)      { p = p2; n = s2; lb = b - nb1; }
    else if (b < nb1 + nb2 + nb3){ p = p3; n = s3; lb = b - nb1 - nb2; }
    else                         { p = p4; n = s4; lb = b - nb1 - nb2 - nb3; }
    int i = lb * 256 + threadIdx.x;
    if (i < n) p[i] = 0;
}

__global__ void hist3_k(const int* e1, int E1, int* c1,
                        const int* e2, int E2, int* c2,
                        const int* e3, int E3, int* c3, int nb1, int nb2) {
    int b = blockIdx.x; const int* dst; int* c; int E; int lb;
    if (b < nb1)            { dst = e1 + E1; c = c1; E = E1; lb = b; }
    else if (b < nb1 + nb2) { dst = e2 + E2; c = c2; E = E2; lb = b - nb1; }
    else                    { dst = e3 + E3; c = c3; E = E3; lb = b - nb1 - nb2; }
    int e = lb * 256 + threadIdx.x;
    if (e < E) atomicAdd(&c[dst[e]], 1);
}

__device__ __forceinline__ void scan1_body(const int* __restrict__ cnt, int* __restrict__ rs,
                                           int* __restrict__ bsum, int n1, int n, int lb) {
    __shared__ int wsum[4];
    int t = threadIdx.x;
    int base = lb * 1024 + t * 4;
    int v[4]; int s = 0;
#pragma unroll
    for (int i = 0; i < 4; ++i) { int idx = base + i; v[i] = s; s += (idx < n) ? cnt[idx] : 0; }
    int lane = t & 63, wv = t >> 6;
    int x = s;
#pragma unroll
    for (int off = 1; off < 64; off <<= 1) { int y = __shfl_up(x, off, 64); if (lane >= off) x += y; }
    if (lane == 63) wsum[wv] = x;
    __syncthreads();
    int woff = 0;
    for (int w = 0; w < wv; ++w) woff += wsum[w];
    int excl = woff + (x - s);
#pragma unroll
    for (int i = 0; i < 4; ++i) { int idx = base + i; if (idx < n1) rs[idx] = excl + v[i]; }
    if (t == 255) bsum[lb] = wsum[0] + wsum[1] + wsum[2] + wsum[3];
}

__global__ void scan1_3k(const int* c1, int* r1, int* b1, int n1a, int na,
                         const int* c2, int* r2, int* b2, int n1b, int nb,
                         const int* c3, int* r3, int* b3, int n1c, int nc,
                         int nbl1, int nbl2) {
    int b = blockIdx.x;
    if (b < nbl1)             scan1_body(c1, r1, b1, n1a, na, b);
    else if (b < nbl1 + nbl2) scan1_body(c2, r2, b2, n1b, nb, b - nbl1);
    else                      scan1_body(c3, r3, b3, n1c, nc, b - nbl1 - nbl2);
}

__device__ __forceinline__ void scan2_body(int* bsum, int nb, int* wsum) {
    int t = threadIdx.x;
    int s = (t < nb) ? bsum[t] : 0;
    int lane = t & 63, wv = t >> 6;
    int x = s;
#pragma unroll
    for (int off = 1; off < 64; off <<= 1) { int y = __shfl_up(x, off, 64); if (lane >= off) x += y; }
    if (lane == 63) wsum[wv] = x;
    __syncthreads();
    int woff = 0;
    for (int w = 0; w < wv; ++w) woff += wsum[w];
    if (t < nb) bsum[t] = woff + x - s;
    __syncthreads();
}

__global__ void scan2_3k(int* b1, int nb1, int* b2, int nb2, int* b3, int nb3) {
    __shared__ int wsum[4];
    scan2_body(b1, nb1, wsum);
    scan2_body(b2, nb2, wsum);
    scan2_body(b3, nb3, wsum);
}

__global__ void scan3_3k(int* r1, const int* b1, int n1a,
                         int* r2, const int* b2, int n1b,
                         int* r3, const int* b3, int n1c, int nc1, int nc2) {
    int b = blockIdx.x; int* rs; const int* bsum; int n1; int lb;
    if (b < nc1)            { rs = r1; bsum = b1; n1 = n1a; lb = b; }
    else if (b < nc1 + nc2) { rs = r2; bsum = b2; n1 = n1b; lb = b - nc1; }
    else                    { rs = r3; bsum = b3; n1 = n1c; lb = b - nc1 - nc2; }
    int i = lb * 256 + threadIdx.x;
    if (i < n1) rs[i] += bsum[lb >> 2];
}

__global__ void fill3_k(const int* e1, int E1, const int* r1, int* c1, int* s1,
                        const int* e2, int E2, const int* r2, int* c2, int* s2,
                        const int* e3, int E3, const int* r3, int* c3, int* s3,
                        int nb1, int nb2) {
    int b = blockIdx.x;
    const int* edges; int E; const int* rs; int* cur; int* csrc; int lb;
    if (b < nb1)            { edges = e1; E = E1; rs = r1; cur = c1; csrc = s1; lb = b; }
    else if (b < nb1 + nb2) { edges = e2; E = E2; rs = r2; cur = c2; csrc = s2; lb = b - nb1; }
    else                    { edges = e3; E = E3; rs = r3; cur = c3; csrc = s3; lb = b - nb1 - nb2; }
    int e = lb * 256 + threadIdx.x;
    if (e >= E) return;
    int d = edges[E + e];
    int p = rs[d] + atomicAdd(&cur[d], 1);
    csrc[p] = edges[e];
}

// -------- gather + relu with bf16 messages:
// z[j] = relu(z[j] + sum_{k in row j} m[csrc[k]])  (m in bf16, z fp32)
__global__ void neighsum_relu_k(const int* __restrict__ rs, const int* __restrict__ csrc,
                                const bf162* __restrict__ m, float* __restrict__ z,
                                int R, int nb8) {
    int b = (int)(blockIdx.x & 7) * nb8 + (int)(blockIdx.x >> 3);
    int t = threadIdx.x;
    int wv = t >> 6, lane = t & 63;
    int j = b * 8 + wv * 2 + (lane >> 5);   // 8 rows per block
    int f2 = lane & 31;
    if (j >= R) return;
    float2* z2p = (float2*)z;
    int s = rs[j], e = rs[j + 1];
    float2 a = z2p[(size_t)j * 32 + f2];
    float ax = a.x, ay = a.y;
    int k = s;
    for (; k + 8 <= e; k += 8) {
        int i0 = csrc[k],     i1 = csrc[k + 1], i2 = csrc[k + 2], i3 = csrc[k + 3];
        int i4 = csrc[k + 4], i5 = csrc[k + 5], i6 = csrc[k + 6], i7 = csrc[k + 7];
        bf162 v0 = m[(size_t)i0 * 32 + f2], v1 = m[(size_t)i1 * 32 + f2];
        bf162 v2 = m[(size_t)i2 * 32 + f2], v3 = m[(size_t)i3 * 32 + f2];
        bf162 v4 = m[(size_t)i4 * 32 + f2], v5 = m[(size_t)i5 * 32 + f2];
        bf162 v6 = m[(size_t)i6 * 32 + f2], v7 = m[(size_t)i7 * 32 + f2];
        ax += ((bl(v0.x) + bl(v1.x)) + (bl(v2.x) + bl(v3.x)))
            + ((bl(v4.x) + bl(v5.x)) + (bl(v6.x) + bl(v7.x)));
        ay += ((bl(v0.y) + bl(v1.y)) + (bl(v2.y) + bl(v3.y)))
            + ((bl(v4.y) + bl(v5.y)) + (bl(v6.y) + bl(v7.y)));
    }
    for (; k + 4 <= e; k += 4) {
        int i0 = csrc[k], i1 = csrc[k + 1], i2 = csrc[k + 2], i3 = csrc[k + 3];
        bf162 v0 = m[(size_t)i0 * 32 + f2], v1 = m[(size_t)i1 * 32 + f2];
        bf162 v2 = m[(size_t)i2 * 32 + f2], v3 = m[(size_t)i3 * 32 + f2];
        ax += (bl(v0.x) + bl(v1.x)) + (bl(v2.x) + bl(v3.x));
        ay += (bl(v0.y) + bl(v1.y)) + (bl(v2.y) + bl(v3.y));
    }
    for (; k < e; ++k) {
        bf162 v = m[(size_t)csrc[k] * 32 + f2];
        ax += bl(v.x); ay += bl(v.y);
    }
    z2p[(size_t)j * 32 + f2] = make_float2(fmaxf(ax, 0.f), fmaxf(ay, 0.f));
}

// -------- level-2 layer-0 combined gather: writes z-init (fp32) AND m (bf16).
// Streaming over rows: 4 independent table gathers/row, W coeffs hoisted over
// 4 rows/thread. (R12 lesson: per-row init inside the edge-loop kernel doubles
// exposed latency; R11 lesson: per-EDGE init is 3x worse. Materialize here.)
__global__ void gatherZM2_k(const float* __restrict__ hU1, const float* __restrict__ hV1,
                            const float* __restrict__ hU2, const float* __restrict__ hV2,
                            const int* __restrict__ gu, const int* __restrict__ gv,
                            const float* __restrict__ iso2,
                            const float* __restrict__ W1, const float* __restrict__ W2,
                            float* __restrict__ z, bf16* __restrict__ m,
                            int n2, int jstep) {
    int idx = blockIdx.x * 256 + threadIdx.x;
    int j = idx >> 6, f = idx & 63;
    float w1c = W1[f * 129 + 128], w2c = W2[f * 129 + 128];
#pragma unroll
    for (int r = 0; r < 4; ++r, j += jstep) {
        if (j >= n2) return;          // j uniform across the 64-lane group
        int u = gu[j], v = gv[j];
        float is = iso2[j];
        z[(size_t)j * HID + f] = hU1[u * HID + f] + hV1[v * HID + f] + is * w1c;
        m[(size_t)j * HID + f] =
            __float2bfloat16(hU2[u * HID + f] + hV2[v * HID + f] + is * w2c);
    }
}

// -------- level-3 layer-0 combined gather (iso3 one-hot x4)
__global__ void gatherZM3_k(const float* __restrict__ hA1, const float* __restrict__ hB1,
                            const float* __restrict__ hC1,
                            const float* __restrict__ hA2, const float* __restrict__ hB2,
                            const float* __restrict__ hC2,
                            const int* __restrict__ ga, const int* __restrict__ gb,
                            const int* __restrict__ gc, const float* __restrict__ iso3,
                            const float* __restrict__ W1, const float* __restrict__ W2,
                            float* __restrict__ z, bf16* __restrict__ m,
                            int n3, int jstep) {
    int idx = blockIdx.x * 256 + threadIdx.x;
    int j = idx >> 6, f = idx & 63;
    float w1c[4], w2c[4];
#pragma unroll
    for (int c = 0; c < 4; ++c) {
        w1c[c] = W1[f * 196 + 192 + c];
        w2c[c] = W2[f * 196 + 192 + c];
    }
    const float4* I4 = (const float4*)iso3;
#pragma unroll
    for (int r = 0; r < 4; ++r, j += jstep) {
        if (j >= n3) return;
        int a = ga[j], b = gb[j], c = gc[j];
        float4 iv = I4[j];
        float zz = hA1[a * HID + f] + hB1[b * HID + f] + hC1[c * HID + f]
                 + iv.x * w1c[0] + iv.y * w1c[1] + iv.z * w1c[2] + iv.w * w1c[3];
        float mm = hA2[a * HID + f] + hB2[b * HID + f] + hC2[c * HID + f]
                 + iv.x * w2c[0] + iv.y * w2c[1] + iv.z * w2c[2] + iv.w * w2c[3];
        z[(size_t)j * HID + f] = zz;
        m[(size_t)j * HID + f] = __float2bfloat16(mm);
    }
}

// -------- split segment sum
__global__ void segsum_split_k(const float* __restrict__ h, float* __restrict__ comb,
                               int per, int coloff, int S, int chunk) {
    int b = blockIdx.x;
    int g = b / S, s = b % S;
    int f = threadIdx.x;
    int r0 = s * chunk;
    int r1 = min(per, r0 + chunk);
    float acc = 0.f;
    const float* p = h + ((size_t)g * per + r0) * HID + f;
    for (int r = r0; r < r1; ++r) { acc += *p; p += HID; }
    atomicAdd(&comb[g * 192 + coloff + f], acc);
}

// -------- classifier
__global__ void classifier_k(const float* __restrict__ comb,
                             const float* __restrict__ cW1, const float* __restrict__ cb1,
                             const float* __restrict__ cW2, const float* __restrict__ cb2,
                             float* __restrict__ out) {
    __shared__ float row[192];
    __shared__ float hid[64];
    int g = blockIdx.x, t = threadIdx.x;
    for (int i = t; i < 192; i += 64) row[i] = comb[g * 192 + i];
    __syncthreads();
    float acc = cb1[t];
#pragma unroll 8
    for (int k = 0; k < 192; ++k) acc += row[k] * cW1[t * 192 + k];
    hid[t] = fmaxf(acc, 0.f);
    __syncthreads();
    if (t < 10) {
        float o = cb2[t];
#pragma unroll
        for (int k = 0; k < 64; ++k) o += hid[k] * cW2[t * 64 + k];
        out[g * 10 + t] = o;
    }
}

static inline int cdiv(long long a, long long b) { return (int)((a + b - 1) / b); }

extern "C" void kernel_launch(void* const* d_in, const int* in_sizes, int n_in,
                              void* d_out, int out_size, void* d_ws, size_t ws_size,
                              hipStream_t stream) {
    const float* x        = (const float*)d_in[0];
    const int*   eidx     = (const int*)d_in[1];
    const int*   gu2      = (const int*)d_in[3];
    const int*   gv2      = (const int*)d_in[4];
    const float* iso2     = (const float*)d_in[5];
    const int*   tedges   = (const int*)d_in[6];
    const int*   ga3      = (const int*)d_in[8];
    const int*   gb3      = (const int*)d_in[9];
    const int*   gc3      = (const int*)d_in[10];
    const float* iso3     = (const float*)d_in[11];
    const int*   hedges   = (const int*)d_in[12];
    const float* g1W1[3]  = {(const float*)d_in[14], (const float*)d_in[16], (const float*)d_in[18]};
    const float* g1W2[3]  = {(const float*)d_in[15], (const float*)d_in[17], (const float*)d_in[19]};
    const float* g2W1_0   = (const float*)d_in[20];
    const float* g2W2_0   = (const float*)d_in[21];
    const float* g2W1_1   = (const float*)d_in[22];
    const float* g2W2_1   = (const float*)d_in[23];
    const float* g3W1_0   = (const float*)d_in[24];
    const float* g3W2_0   = (const float*)d_in[25];
    const float* g3W1_1   = (const float*)d_in[26];
    const float* g3W2_1   = (const float*)d_in[27];
    const float* cW1      = (const float*)d_in[28];
    const float* cb1      = (const float*)d_in[29];
    const float* cW2      = (const float*)d_in[30];
    const float* cb2      = (const float*)d_in[31];
    float* out = (float*)d_out;

    const int N  = in_sizes[0] / 32;       // 2560
    const int E1 = in_sizes[1] / 2;
    const int n2 = in_sizes[3];            // 24320
    const int E2 = in_sizes[6] / 2;
    const int n3 = in_sizes[8];            // 145920
    const int E3 = in_sizes[12] / 2;
    const int G  = out_size / 10;          // 128
    const int per1 = N / G, per2 = n2 / G, per3 = n3 / G;

    // ---- workspace carve-up (float units)
    float* ws = (float*)d_ws;
    size_t off = 0;
    auto alloc = [&](size_t n) { float* p = ws + off; off += n; return p; };
    const size_t NH = (size_t)N * HID;
    float* nb0 = alloc(NH); float* nb1 = alloc(NH);
    bf16* mb1 = (bf16*)alloc(NH / 2 + 64);                 // level-1 messages (bf16)
    float* hU1 = alloc(NH); float* hV1 = alloc(NH); float* hU2 = alloc(NH); float* hV2 = alloc(NH);
    float* hA1 = alloc(NH); float* hB1 = alloc(NH); float* hC1 = alloc(NH);
    float* hA2 = alloc(NH); float* hB2 = alloc(NH); float* hC2 = alloc(NH);
    float* z2 = alloc((size_t)n2 * HID);
    bf16* m2b = (bf16*)alloc((size_t)n2 * HID / 2 + 64);   // level-2 messages (bf16)
    float* z3 = alloc((size_t)n3 * HID);
    bf16* m3b = (bf16*)alloc((size_t)n3 * HID / 2 + 64);   // level-3 messages (bf16)
    float* comb = alloc((size_t)G * 192);
    int* iws = (int*)(ws + off);
    size_t ioff = 0;
    auto ialloc = [&](size_t n) { int* p = iws + ioff; ioff += n; return p; };
    int* rs1 = ialloc(N + 1);  int* cur1 = ialloc(N);  int* csrc1 = ialloc(E1);
    int* rs2 = ialloc(n2 + 1); int* cur2 = ialloc(n2); int* csrc2 = ialloc(E2);
    int* rs3 = ialloc(n3 + 1); int* cur3 = ialloc(n3); int* csrc3 = ialloc(E3);
    int* bsum1 = ialloc(256); int* bsum2 = ialloc(256); int* bsum3 = ialloc(256);
    (void)ws_size;

    dim3 B256(256);
    auto gemm2 = [&](const float* in, const float* Wa, const float* Wb,
                     float* oa, float* ob, int R, int K, int ldw, int coloff) {
        int blocks = cdiv(cdiv(R, RPW), 4);
        if (K == 64)
            gemm2_reg<64><<<blocks, B256, 0, stream>>>(in, Wa, Wb, oa, ob, R, ldw, coloff);
        else
            gemm2_reg<32><<<blocks, B256, 0, stream>>>(in, Wa, Wb, oa, ob, R, ldw, coloff);
    };
    auto gemm2b = [&](const float* in, const float* Wa, const float* Wb,
                      float* oa, bf16* ob, int R, int K, int ldw, int coloff) {
        int blocks = cdiv(cdiv(R, RPW), 4);
        if (K == 64)
            gemm2_regb<64><<<blocks, B256, 0, stream>>>(in, Wa, Wb, oa, ob, R, ldw, coloff);
        else
            gemm2_regb<32><<<blocks, B256, 0, stream>>>(in, Wa, Wb, oa, ob, R, ldw, coloff);
    };
    auto neigh = [&](const int* rs, const int* csrc, const bf16* m, float* z, int R) {
        int nb = cdiv(R, 8);
        int nb8 = cdiv(nb, 8);
        neighsum_relu_k<<<nb8 * 8, B256, 0, stream>>>(rs, csrc, (const bf162*)m, z, R, nb8);
    };
    auto segsum = [&](const float* h, int per, int coloff) {
        int chunk = 64;
        int S = cdiv(per, chunk);
        segsum_split_k<<<G * S, 64, 0, stream>>>(h, comb, per, coloff, S, chunk);
    };

    // ---- batched CSR build (7 dispatches; comb zero folded into first)
    int nz1 = cdiv(N, 256), nz2 = cdiv(n2, 256), nz3 = cdiv(n3, 256), nz4 = cdiv(G * 192, 256);
    zero4_k<<<nz1 + nz2 + nz3 + nz4, B256, 0, stream>>>(
        cur1, N, cur2, n2, cur3, n3, (int*)comb, G * 192, nz1, nz2, nz3);
    int ne1 = cdiv(E1, 256), ne2 = cdiv(E2, 256), ne3 = cdiv(E3, 256);
    hist3_k<<<ne1 + ne2 + ne3, B256, 0, stream>>>(
        eidx, E1, cur1, tedges, E2, cur2, hedges, E3, cur3, ne1, ne2);
    int ns1 = cdiv(N + 1, 1024), ns2 = cdiv(n2 + 1, 1024), ns3 = cdiv(n3 + 1, 1024);
    scan1_3k<<<ns1 + ns2 + ns3, B256, 0, stream>>>(
        cur1, rs1, bsum1, N + 1, N, cur2, rs2, bsum2, n2 + 1, n2,
        cur3, rs3, bsum3, n3 + 1, n3, ns1, ns2);
    scan2_3k<<<1, B256, 0, stream>>>(bsum1, ns1, bsum2, ns2, bsum3, ns3);
    int nc1 = cdiv(N + 1, 256), nc2 = cdiv(n2 + 1, 256), nc3 = cdiv(n3 + 1, 256);
    scan3_3k<<<nc1 + nc2 + nc3, B256, 0, stream>>>(
        rs1, bsum1, N + 1, rs2, bsum2, n2 + 1, rs3, bsum3, n3 + 1, nc1, nc2);
    zero4_k<<<nz1 + nz2 + nz3, B256, 0, stream>>>(
        cur1, N, cur2, n2, cur3, n3, nullptr, 0, nz1, nz2, nz3);
    fill3_k<<<ne1 + ne2 + ne3, B256, 0, stream>>>(
        eidx, E1, rs1, cur1, csrc1, tedges, E2, rs2, cur2, csrc2,
        hedges, E3, rs3, cur3, csrc3, ne1, ne2);

    // ================= level 1: node GNN (3 layers; bf16 messages) ==========
    const float* hcur = x;
    float* zb[2] = {nb0, nb1};
    for (int l = 0; l < 3; ++l) {
        int K = (l == 0) ? 32 : 64;
        float* z = zb[l & 1];
        gemm2b(hcur, g1W1[l], g1W2[l], z, mb1, N, K, K, 0);
        neigh(rs1, csrc1, mb1, z, N);
        hcur = z;
    }
    const float* h = hcur;   // = nb0 after 3 layers

    segsum(h, per1, 0);

    // ================= level 2: pair GNN (2 layers) =================
    gemm2(h, g2W1_0, g2W2_0, hU1, hU2, N, 64, 129, 0);
    gemm2(h, g2W1_0, g2W2_0, hV1, hV2, N, 64, 129, 64);
    {
        int jstep = cdiv(n2, 4);
        gatherZM2_k<<<cdiv((long long)jstep * 64, 256), B256, 0, stream>>>(
            hU1, hV1, hU2, hV2, gu2, gv2, iso2, g2W1_0, g2W2_0, z2, m2b, n2, jstep);
    }
    neigh(rs2, csrc2, m2b, z2, n2);
    gemm2b(z2, g2W1_1, g2W2_1, z2, m2b, n2, 64, 64, 0);   // in-place z2
    neigh(rs2, csrc2, m2b, z2, n2);
    segsum(z2, per2, 64);

    // ================= level 3: triple GNN (2 layers) =================
    gemm2(h, g3W1_0, g3W2_0, hA1, hA2, N, 64, 196, 0);
    gemm2(h, g3W1_0, g3W2_0, hB1, hB2, N, 64, 196, 64);
    gemm2(h, g3W1_0, g3W2_0, hC1, hC2, N, 64, 196, 128);
    {
        int jstep = cdiv(n3, 4);
        gatherZM3_k<<<cdiv((long long)jstep * 64, 256), B256, 0, stream>>>(
            hA1, hB1, hC1, hA2, hB2, hC2, ga3, gb3, gc3, iso3,
            g3W1_0, g3W2_0, z3, m3b, n3, jstep);
    }
    neigh(rs3, csrc3, m3b, z3, n3);
    gemm2b(z3, g3W1_1, g3W2_1, z3, m3b, n3, 64, 64, 0);   // in-place z3
    neigh(rs3, csrc3, m3b, z3, n3);
    segsum(z3, per3, 128);

    // ================= classifier =================
    classifier_k<<<G, 64, 0, stream>>>(comb, cW1, cb1, cW2, cb2, out);
}